// Round 2
// baseline (302.944 us; speedup 1.0000x reference)
//
#include <hip/hip_runtime.h>
#include <math.h>

// Problem constants
#define BB 32
#define NN 1024
#define DD 768
#define KK 512
#define MM (BB * NN)  // 32768 token rows

typedef _Float16 half8 __attribute__((ext_vector_type(8)));
typedef _Float16 half4 __attribute__((ext_vector_type(4)));
typedef float floatx4 __attribute__((ext_vector_type(4)));

// async global(16B) -> LDS, per-lane dest = uniform base + lane*16
__device__ __forceinline__ void load_lds16(const void* g, void* l) {
    __builtin_amdgcn_global_load_lds(
        (const __attribute__((address_space(1))) unsigned int*)g,
        (__attribute__((address_space(3))) unsigned int*)l, 16, 0, 0);
}

__device__ __forceinline__ void mem_fence_sched() {
    asm volatile("" ::: "memory");
    __builtin_amdgcn_sched_barrier(0);
}

// ---------------------------------------------------------------------------
// cast fp32 -> fp16 (codebook only)
// ---------------------------------------------------------------------------
__global__ __launch_bounds__(256) void cast_f32_f16(const float* __restrict__ src,
                                                    _Float16* __restrict__ dst,
                                                    int n8) {
    int i = blockIdx.x * 256 + threadIdx.x;
    if (i >= n8) return;
    float4 a = ((const float4*)src)[2 * i];
    float4 b = ((const float4*)src)[2 * i + 1];
    half8 h;
    h[0] = (_Float16)a.x; h[1] = (_Float16)a.y; h[2] = (_Float16)a.z; h[3] = (_Float16)a.w;
    h[4] = (_Float16)b.x; h[5] = (_Float16)b.y; h[6] = (_Float16)b.z; h[7] = (_Float16)b.w;
    ((half8*)dst)[i] = h;
}

// ---------------------------------------------------------------------------
// csq[k] = sum_d codebook[k][d]^2
// ---------------------------------------------------------------------------
__global__ __launch_bounds__(256) void csq_kernel(const float* __restrict__ cb,
                                                  float* __restrict__ csq) {
    int k = blockIdx.x;
    const float* row = cb + (size_t)k * DD;
    float s = 0.f;
    for (int d = threadIdx.x; d < DD; d += 256) {
        float v = row[d];
        s += v * v;
    }
    #pragma unroll
    for (int off = 32; off > 0; off >>= 1) s += __shfl_down(s, off);
    __shared__ float sm[4];
    int lane = threadIdx.x & 63, wid = threadIdx.x >> 6;
    if (lane == 0) sm[wid] = s;
    __syncthreads();
    if (threadIdx.x == 0) csq[k] = sm[0] + sm[1] + sm[2] + sm[3];
}

// ---------------------------------------------------------------------------
// FUSED v4: logits (MFMA fp16) + softmax + transposed St write.
// Block = 512 threads (8 waves) = 64 tokens x all 512 k; wave w owns k-slab
//   [w*64, w*64+64) (64x64 wave tile, 8 frag reads / 16 MFMA per K-step).
// T3+T4 pipeline: raw s_barrier + COUNTED vmcnt. Per iter the barrier waits
//   vmcnt(1) lgkmcnt(0): drains the Cs lds-dma + the X load needed next iter,
//   leaves the youngest X prefetch (2-deep) in flight across the barrier.
//   (__syncthreads would drain vmcnt(0) -> exposes HBM latency every iter.)
// XOR swizzle (16B unit ^= (row>>1)&3) on all LDS tiles: conflict-free frag
//   reads; lds-dma uses linear dest + pre-swizzled global source.
// ---------------------------------------------------------------------------
__global__ __launch_bounds__(512, 4) void fused_logits_softmax(
    const float* __restrict__ X,        // [M, D] fp32
    const _Float16* __restrict__ Cbh,   // [K, D] fp16
    const float* __restrict__ csq,      // [K]
    _Float16* __restrict__ St)          // [B, K, N] fp16
{
    __shared__ _Float16 Cs[2][512][32];   // 64 KB double-buffered codebook chunk
    __shared__ _Float16 Xs[2][64][32];    // 8 KB double-buffered token chunk
    __shared__ float redbuf[8][64];       // per-wave softmax partials
    __shared__ float gred[64];            // reduced per-token value

    const int t = threadIdx.x;
    const int w = t >> 6;
    const int lane = t & 63;
    const int l15 = lane & 15;
    const int quad = lane >> 4;
    const int wk = w * 64;              // this wave's k slab
    const int gm0 = blockIdx.x * 64;    // global token base

    // swizzled 16B-unit column for fragment reads
    const int qs = (quad ^ ((l15 >> 1) & 3)) * 8;

    float cs[4];
    #pragma unroll
    for (int ki = 0; ki < 4; ki++) cs[ki] = csq[wk + ki * 16 + l15];

    floatx4 acc[4][4] = {};

    // --- Cs staging: all 512 threads x 4 units; row=c*128+(t>>2), phys q=t&3,
    //     source col-chunk swizzled: cq = (t&3) ^ ((t>>3)&3)
    const int cr = t >> 2;
    const int cq = (t & 3) ^ ((t >> 3) & 3);

    // --- X staging: ALL 512 threads, one float4 (16B fp32 -> 8B fp16) each
    //     -> uniform 1 VMEM load per wave per iter (exact vmcnt counting)
    const int xr = t >> 3;              // row 0..63
    const int xc = (t & 7) * 4;         // col 0..28
    const int xq = (t & 7) >> 1;        // 16B unit
    const int xoff = xr * 32 + (xq ^ ((xr >> 1) & 3)) * 8 + (xc & 7);  // phys halfs
    const float* xsrc = X + (size_t)(gm0 + xr) * DD + xc;

    // ---- prologue: stage chunk 0, prefetch X chunks 1,2 ----
    #pragma unroll
    for (int c = 0; c < 4; c++)
        load_lds16(Cbh + (size_t)(c * 128 + cr) * DD + cq * 8,
                   (_Float16*)Cs[0] + (c * 512 + t) * 8);
    float4 xv0 = *(const float4*)xsrc;          // chunk 0
    float4 xn1 = *(const float4*)(xsrc + 32);   // chunk 1
    float4 xn2 = *(const float4*)(xsrc + 64);   // chunk 2
    {
        half4 h;
        h[0] = (_Float16)xv0.x; h[1] = (_Float16)xv0.y;
        h[2] = (_Float16)xv0.z; h[3] = (_Float16)xv0.w;
        *(half4*)((_Float16*)Xs[0] + xoff) = h;
    }
    __syncthreads();   // prologue: full drain is fine (once)

    for (int it = 0; it < 24; ++it) {
        const int cur = it & 1;
        if (it < 23) {
            // stage chunk it+1: convert xn1 (data loaded 2 iters ago; already
            // drained by previous barrier's vmcnt(1) -> no stall here)
            half4 h;
            h[0] = (_Float16)xn1.x; h[1] = (_Float16)xn1.y;
            h[2] = (_Float16)xn1.z; h[3] = (_Float16)xn1.w;
            *(half4*)((_Float16*)Xs[cur ^ 1] + xoff) = h;
            const int d0n = (it + 1) * 32;
            #pragma unroll
            for (int c = 0; c < 4; c++)
                load_lds16(Cbh + (size_t)(c * 128 + cr) * DD + d0n + cq * 8,
                           (_Float16*)Cs[cur ^ 1] + (c * 512 + t) * 8);
            // fence: keep the 4 lds-dma OLDER than the X prefetch so the
            // barrier's vmcnt(1) is exact
            mem_fence_sched();
            xn1 = xn2;
            if (it < 21) xn2 = *(const float4*)(xsrc + (it + 3) * 32);
        }
        // compute chunk it from buffer cur
        half8 af[4], bf[4];
        #pragma unroll
        for (int mi = 0; mi < 4; mi++)
            af[mi] = *(half8*)((_Float16*)Xs[cur] + (mi * 16 + l15) * 32 + qs);
        #pragma unroll
        for (int ki = 0; ki < 4; ki++)
            bf[ki] = *(half8*)((_Float16*)Cs[cur] + (wk + ki * 16 + l15) * 32 + qs);
        #pragma unroll
        for (int mi = 0; mi < 4; mi++)
            #pragma unroll
            for (int ki = 0; ki < 4; ki++)
                acc[mi][ki] = __builtin_amdgcn_mfma_f32_16x16x32_f16(af[mi], bf[ki], acc[mi][ki], 0, 0, 0);
        if (it < 23) {
            // counted barrier: drain lds-dma + the X load consumed next iter,
            // keep the youngest X prefetch in flight
            if (it < 21) asm volatile("s_waitcnt vmcnt(1) lgkmcnt(0)" ::: "memory");
            else         asm volatile("s_waitcnt vmcnt(0) lgkmcnt(0)" ::: "memory");
            __builtin_amdgcn_s_barrier();
            __builtin_amdgcn_sched_barrier(0);
        }
    }

    // ---- softmax over k=512 ----
    // logit = 2*acc - cs;  k = wk + ki*16 + l15, token = mi*16 + quad*4 + r
    float pmax[4][4];
    #pragma unroll
    for (int mi = 0; mi < 4; mi++)
        #pragma unroll
        for (int r = 0; r < 4; r++) {
            float m = -1e30f;
            #pragma unroll
            for (int ki = 0; ki < 4; ki++)
                m = fmaxf(m, 2.f * acc[mi][ki][r] - cs[ki]);
            pmax[mi][r] = m;
        }
    #pragma unroll
    for (int off = 1; off < 16; off <<= 1)
        #pragma unroll
        for (int mi = 0; mi < 4; mi++)
            #pragma unroll
            for (int r = 0; r < 4; r++)
                pmax[mi][r] = fmaxf(pmax[mi][r], __shfl_xor(pmax[mi][r], off));
    if (l15 == 0) {
        #pragma unroll
        for (int mi = 0; mi < 4; mi++)
            #pragma unroll
            for (int r = 0; r < 4; r++)
                redbuf[w][mi * 16 + quad * 4 + r] = pmax[mi][r];
    }
    __syncthreads();
    if (t < 64) {
        float g = redbuf[0][t];
        #pragma unroll
        for (int wv = 1; wv < 8; wv++) g = fmaxf(g, redbuf[wv][t]);
        gred[t] = g;
    }
    __syncthreads();
    float gmax[4][4];
    #pragma unroll
    for (int mi = 0; mi < 4; mi++)
        #pragma unroll
        for (int r = 0; r < 4; r++)
            gmax[mi][r] = gred[mi * 16 + quad * 4 + r];   // broadcast read

    float psum[4][4] = {};
    #pragma unroll
    for (int mi = 0; mi < 4; mi++)
        #pragma unroll
        for (int ki = 0; ki < 4; ki++) {
            floatx4 e;
            #pragma unroll
            for (int r = 0; r < 4; r++) {
                e[r] = __expf(2.f * acc[mi][ki][r] - cs[ki] - gmax[mi][r]);
                psum[mi][r] += e[r];
            }
            acc[mi][ki] = e;
        }
    #pragma unroll
    for (int off = 1; off < 16; off <<= 1)
        #pragma unroll
        for (int mi = 0; mi < 4; mi++)
            #pragma unroll
            for (int r = 0; r < 4; r++)
                psum[mi][r] += __shfl_xor(psum[mi][r], off);
    if (l15 == 0) {
        #pragma unroll
        for (int mi = 0; mi < 4; mi++)
            #pragma unroll
            for (int r = 0; r < 4; r++)
                redbuf[w][mi * 16 + quad * 4 + r] = psum[mi][r];
    }
    __syncthreads();
    if (t < 64) {
        float s = redbuf[0][t];
        #pragma unroll
        for (int wv = 1; wv < 8; wv++) s += redbuf[wv][t];
        gred[t] = 1.f / s;
    }
    __syncthreads();
    float ginv[4][4];
    #pragma unroll
    for (int mi = 0; mi < 4; mi++)
        #pragma unroll
        for (int r = 0; r < 4; r++)
            ginv[mi][r] = gred[mi * 16 + quad * 4 + r];

    // scale + transposed store: St[b][k][n]
    const int b = gm0 >> 10;
    const int n0 = gm0 & 1023;
    #pragma unroll
    for (int mi = 0; mi < 4; mi++)
        #pragma unroll
        for (int ki = 0; ki < 4; ki++) {
            half4 s4;
            #pragma unroll
            for (int r = 0; r < 4; r++)
                s4[r] = (_Float16)(acc[mi][ki][r] * ginv[mi][r]);
            int k = wk + ki * 16 + l15;
            *(half4*)&St[((size_t)b * KK + k) * NN + n0 + mi * 16 + quad * 4] = s4;
        }
}

// ---------------------------------------------------------------------------
// Cast+transpose X (fp32 [b][n][d]) -> Xt (fp16 [b][d][n])
// ---------------------------------------------------------------------------
__global__ __launch_bounds__(256) void transpose_xt(const float* __restrict__ X,
                                                    _Float16* __restrict__ Xt) {
    const int n0 = blockIdx.x * 64;
    const int d0 = blockIdx.y * 32;
    const int b = blockIdx.z;
    __shared__ _Float16 Ls[64][40];
    const int t = threadIdx.x;
    const int r = t >> 2, c8 = (t & 3) * 8;
    const float* src = X + ((size_t)(b << 10) + n0 + r) * DD + d0 + c8;
    float4 f0 = *(const float4*)src;
    float4 f1 = *(const float4*)(src + 4);
    half8 h;
    h[0] = (_Float16)f0.x; h[1] = (_Float16)f0.y; h[2] = (_Float16)f0.z; h[3] = (_Float16)f0.w;
    h[4] = (_Float16)f1.x; h[5] = (_Float16)f1.y; h[6] = (_Float16)f1.z; h[7] = (_Float16)f1.w;
    *(half8*)&Ls[r][c8] = h;
    __syncthreads();
    const int dr = t >> 3;          // 0..31
    const int nc = (t & 7) * 8;     // 0..56
    half8 o;
    #pragma unroll
    for (int j = 0; j < 8; j++) o[j] = Ls[nc + j][dr];
    *(half8*)&Xt[((size_t)b * DD + d0 + dr) * NN + n0 + nc] = o;
}

// ---------------------------------------------------------------------------
// GEMM2 v4: out[b][k][d] = sum_n St[b][k][n] * Xt[b][d][n]
// 128x128 tile, BK=32. TRIPLE-buffered LDS (48 KB -> 3 blocks/CU), stage
// issued 2 tiles ahead, raw s_barrier + counted vmcnt(4): the stage needed
// NEXT iter is drained, the just-issued stage stays in flight (~2-iter span).
// ---------------------------------------------------------------------------
__global__ __launch_bounds__(256, 3) void gemm2_mfma(const _Float16* __restrict__ St,
                                                     const _Float16* __restrict__ Xt,
                                                     float* __restrict__ out) {
    __shared__ _Float16 As[3][128][32];  // 24 KB
    __shared__ _Float16 Bs[3][128][32];  // 24 KB

    const int d0 = blockIdx.x * 128;
    const int k0 = blockIdx.y * 128;
    const int b = blockIdx.z;
    const int t = threadIdx.x;
    const int wave = t >> 6;
    const int lane = t & 63;
    const int wm = (wave >> 1) * 64;
    const int wn = (wave & 1) * 64;
    const int l15 = lane & 15;
    const int quad = lane >> 4;
    const int qs = (quad ^ ((l15 >> 1) & 3)) * 8;

    const int cr = t >> 2;                       // row within 64-row group
    const int cq = (t & 3) ^ ((t >> 3) & 3);     // swizzled source col-chunk

    floatx4 acc[4][4] = {};

    const _Float16* Abase = St + ((size_t)b * KK + k0) * NN;
    const _Float16* Bbase = Xt + ((size_t)b * DD + d0) * NN;

    // prologue: stage tiles 0 and 1 (fenced so vmcnt(4) isolates stage 0)
    #pragma unroll
    for (int c = 0; c < 2; c++) {
        load_lds16(Abase + (size_t)(c * 64 + cr) * NN + cq * 8,
                   (_Float16*)As[0] + (c * 256 + t) * 8);
        load_lds16(Bbase + (size_t)(c * 64 + cr) * NN + cq * 8,
                   (_Float16*)Bs[0] + (c * 256 + t) * 8);
    }
    mem_fence_sched();
    #pragma unroll
    for (int c = 0; c < 2; c++) {
        load_lds16(Abase + (size_t)(c * 64 + cr) * NN + 32 + cq * 8,
                   (_Float16*)As[1] + (c * 256 + t) * 8);
        load_lds16(Bbase + (size_t)(c * 64 + cr) * NN + 32 + cq * 8,
                   (_Float16*)Bs[1] + (c * 256 + t) * 8);
    }
    asm volatile("s_waitcnt vmcnt(4)" ::: "memory");   // stage 0 complete
    __builtin_amdgcn_s_barrier();
    __builtin_amdgcn_sched_barrier(0);

    int ic = 0, js = 2;   // compute buffer, stage buffer (= (it+2)%3)
    for (int it = 0; it < 32; ++it) {
        if (it < 30) {
            const int n0s = (it + 2) * 32;
            _Float16* Ad = (_Float16*)As[js];
            _Float16* Bd = (_Float16*)Bs[js];
            #pragma unroll
            for (int c = 0; c < 2; c++) {
                load_lds16(Abase + (size_t)(c * 64 + cr) * NN + n0s + cq * 8,
                           Ad + (c * 256 + t) * 8);
                load_lds16(Bbase + (size_t)(c * 64 + cr) * NN + n0s + cq * 8,
                           Bd + (c * 256 + t) * 8);
            }
        }
        const _Float16* Ar = (const _Float16*)As[ic];
        const _Float16* Br = (const _Float16*)Bs[ic];
        half8 af[4], bf[4];
        #pragma unroll
        for (int i = 0; i < 4; i++)
            af[i] = *(const half8*)(Ar + (wm + i * 16 + l15) * 32 + qs);
        #pragma unroll
        for (int i = 0; i < 4; i++)
            bf[i] = *(const half8*)(Br + (wn + i * 16 + l15) * 32 + qs);
        #pragma unroll
        for (int mi = 0; mi < 4; mi++)
            #pragma unroll
            for (int ni = 0; ni < 4; ni++)
                acc[mi][ni] = __builtin_amdgcn_mfma_f32_16x16x32_f16(af[mi], bf[ni], acc[mi][ni], 0, 0, 0);
        if (it < 31) {
            // drain the stage consumed next iter; keep the newest in flight
            if (it < 30) asm volatile("s_waitcnt vmcnt(4) lgkmcnt(0)" ::: "memory");
            else         asm volatile("s_waitcnt vmcnt(0) lgkmcnt(0)" ::: "memory");
            __builtin_amdgcn_s_barrier();
            __builtin_amdgcn_sched_barrier(0);
        }
        ic = (ic == 2) ? 0 : ic + 1;
        js = (js == 2) ? 0 : js + 1;
    }

    #pragma unroll
    for (int ni = 0; ni < 4; ni++) {
        #pragma unroll
        for (int mi = 0; mi < 4; mi++) {
            int k = k0 + wm + mi * 16 + quad * 4;
            int d = d0 + wn + ni * 16 + l15;
            float* op = out + ((size_t)b * KK + k) * DD + d;
            floatx4 a = acc[mi][ni];
            op[0 * DD] = a[0];
            op[1 * DD] = a[1];
            op[2 * DD] = a[2];
            op[3 * DD] = a[3];
        }
    }
}

// ---------------------------------------------------------------------------
extern "C" void kernel_launch(void* const* d_in, const int* in_sizes, int n_in,
                              void* d_out, int out_size, void* d_ws, size_t ws_size,
                              hipStream_t stream) {
    const float* x  = (const float*)d_in[0];   // [B,N,D] fp32
    const float* cb = (const float*)d_in[1];   // [K,D] fp32
    float* out = (float*)d_out;                // [B,K,D] fp32

    char* ws = (char*)d_ws;
    float*    csq = (float*)ws;                                   // 4 KB
    _Float16* Cbh = (_Float16*)(ws + 4096);                       // 768 KB
    _Float16* Xt  = (_Float16*)(ws + 4096 + 786432);              // 48 MB [b][d][n]
    _Float16* St  = (_Float16*)(ws + 4096 + 786432 + 50331648);   // 32 MB [b][k][n]

    cast_f32_f16<<<(KK * DD / 8 + 255) / 256, 256, 0, stream>>>(cb, Cbh, KK * DD / 8);
    csq_kernel<<<KK, 256, 0, stream>>>(cb, csq);

    // fused logits + softmax -> St (fp16, [b][k][n])
    fused_logits_softmax<<<MM / 64, 512, 0, stream>>>(x, Cbh, csq, St);

    // X -> Xt (fp16, [b][d][n])
    transpose_xt<<<dim3(NN / 64, DD / 32, BB), 256, 0, stream>>>(x, Xt);

    // aggregate
    gemm2_mfma<<<dim3(DD / 128, KK / 128, BB), 256, 0, stream>>>(St, Xt, out);
}

// Round 3
// 274.376 us; speedup vs baseline: 1.1041x; 1.1041x over previous
//
#include <hip/hip_runtime.h>
#include <math.h>

// Problem constants
#define BB 32
#define NN 1024
#define DD 768
#define KK 512
#define MM (BB * NN)  // 32768 token rows

typedef _Float16 half8 __attribute__((ext_vector_type(8)));
typedef _Float16 half4 __attribute__((ext_vector_type(4)));
typedef float floatx4 __attribute__((ext_vector_type(4)));

// async global(16B) -> LDS, per-lane dest = uniform base + lane*16
__device__ __forceinline__ void load_lds16(const void* g, void* l) {
    __builtin_amdgcn_global_load_lds(
        (const __attribute__((address_space(1))) unsigned int*)g,
        (__attribute__((address_space(3))) unsigned int*)l, 16, 0, 0);
}

// ---------------------------------------------------------------------------
// Codebook prep (merged): fp32->fp16 cast + csq[k] = sum_d cb[k][d]^2
// ---------------------------------------------------------------------------
__global__ __launch_bounds__(256) void prep_codebook(const float* __restrict__ cb,
                                                     _Float16* __restrict__ Cbh,
                                                     float* __restrict__ csq) {
    int k = blockIdx.x;
    const float* row = cb + (size_t)k * DD;
    _Float16* orow = Cbh + (size_t)k * DD;
    float s = 0.f;
    for (int d = threadIdx.x; d < DD; d += 256) {
        float v = row[d];
        s += v * v;
        orow[d] = (_Float16)v;   // 2B stores, thread-consecutive -> coalesced
    }
    #pragma unroll
    for (int off = 32; off > 0; off >>= 1) s += __shfl_down(s, off);
    __shared__ float sm[4];
    int lane = threadIdx.x & 63, wid = threadIdx.x >> 6;
    if (lane == 0) sm[wid] = s;
    __syncthreads();
    if (threadIdx.x == 0) csq[k] = sm[0] + sm[1] + sm[2] + sm[3];
}

// ---------------------------------------------------------------------------
// FUSED v5: logits (MFMA fp16) + softmax + transposed St write + Xt write.
// Structure = proven v3 (78 us): dbuf LDS, ONE __syncthreads per K-chunk,
// XOR swizzle (16B unit ^= (row>>1)&3) -> 0 bank conflicts, lds-dma for Cs
// (linear dest + pre-swizzled global source), reg-roundtrip fp32->fp16 for X.
// NEW: each iteration also writes the staged X chunk back to Xt [b][d][n]
// (fp16 transpose), eliminating the standalone transpose_xt kernel and its
// 96 MB re-read of X. Reads Xs columns (cheap), stores 8B coalesced per dr.
// ---------------------------------------------------------------------------
__global__ __launch_bounds__(512, 4) void fused_logits_softmax(
    const float* __restrict__ X,        // [M, D] fp32
    const _Float16* __restrict__ Cbh,   // [K, D] fp16
    const float* __restrict__ csq,      // [K]
    _Float16* __restrict__ St,          // [B, K, N] fp16
    _Float16* __restrict__ Xt)          // [B, D, N] fp16
{
    __shared__ _Float16 Cs[2][512][32];   // 64 KB double-buffered codebook chunk
    __shared__ _Float16 Xs[2][64][32];    // 8 KB double-buffered token chunk
    __shared__ float redbuf[8][64];       // per-wave softmax partials
    __shared__ float gred[64];            // reduced per-token value

    const int t = threadIdx.x;
    const int w = t >> 6;
    const int lane = t & 63;
    const int l15 = lane & 15;
    const int quad = lane >> 4;
    const int wk = w * 64;              // this wave's k slab
    const int gm0 = blockIdx.x * 64;    // global token base
    const int b = gm0 >> 10;
    const int n0 = gm0 & 1023;

    // swizzled 16B-unit column for fragment reads (row swz bits = (l15>>1)&3)
    const int qs = (quad ^ ((l15 >> 1) & 3)) * 8;

    float cs[4];
    #pragma unroll
    for (int ki = 0; ki < 4; ki++) cs[ki] = csq[wk + ki * 16 + l15];

    floatx4 acc[4][4] = {};

    // --- staging roles ---
    // Cs: all 512 threads x 4 units; unit u=c*512+t -> row=c*128+(t>>2), phys q=t&3
    //     source col-chunk = q ^ swz(row) = (t&3) ^ ((t>>3)&3)
    const int cr = t >> 2;
    const int cq = (t & 3) ^ ((t >> 3) & 3);
    // Xs: threads t<256, 16B fp32 x2 -> half8 at phys unit (t&3), row cr
    const float* xsrc = X + (size_t)(gm0 + cr) * DD + cq * 8;

    // Xt write-back role: thread -> (d-row, 4 n-cols); 16 lanes give 128B/d-row
    const int tdr = t >> 4;             // 0..31 (d within chunk)
    const int tn4 = (t & 15) * 4;       // 0..60 (n within block)

    float4 xa, xb;
    if (t < 256) { xa = *(const float4*)xsrc; xb = *(const float4*)(xsrc + 4); }

    // ---- prologue: stage chunk 0, prefetch X chunk 1 ----
    #pragma unroll
    for (int c = 0; c < 4; c++)
        load_lds16(Cbh + (size_t)(c * 128 + cr) * DD + cq * 8,
                   (_Float16*)Cs[0] + (c * 512 + t) * 8);
    if (t < 256) {
        half8 h;
        h[0] = (_Float16)xa.x; h[1] = (_Float16)xa.y; h[2] = (_Float16)xa.z; h[3] = (_Float16)xa.w;
        h[4] = (_Float16)xb.x; h[5] = (_Float16)xb.y; h[6] = (_Float16)xb.z; h[7] = (_Float16)xb.w;
        *(half8*)&Xs[0][cr][(t & 3) * 8] = h;
        xa = *(const float4*)(xsrc + 32);
        xb = *(const float4*)(xsrc + 36);
    }
    __syncthreads();

    int cur = 0;
    for (int it = 0; it < 24; ++it) {
        const int d0 = it * 32;
        // stage chunk it+1 into the other buffer (latency hides under compute)
        if (it + 1 < 24) {
            const int d0n = d0 + 32;
            #pragma unroll
            for (int c = 0; c < 4; c++)
                load_lds16(Cbh + (size_t)(c * 128 + cr) * DD + d0n + cq * 8,
                           (_Float16*)Cs[cur ^ 1] + (c * 512 + t) * 8);
            if (t < 256) {
                half8 h;
                h[0] = (_Float16)xa.x; h[1] = (_Float16)xa.y; h[2] = (_Float16)xa.z; h[3] = (_Float16)xa.w;
                h[4] = (_Float16)xb.x; h[5] = (_Float16)xb.y; h[6] = (_Float16)xb.z; h[7] = (_Float16)xb.w;
                *(half8*)&Xs[cur ^ 1][cr][(t & 3) * 8] = h;
                if (it + 2 < 24) {
                    xa = *(const float4*)(xsrc + (it + 2) * 32);
                    xb = *(const float4*)(xsrc + (it + 2) * 32 + 4);
                }
            }
        }
        // Xt write-back of current chunk (reads Xs[cur] columns, 8B store)
        {
            half4 xo;
            #pragma unroll
            for (int j = 0; j < 4; j++) {
                int n = tn4 + j;
                xo[j] = *((const _Float16*)Xs[cur] + n * 32 +
                          (((tdr >> 3) ^ ((n >> 1) & 3)) << 3) + (tdr & 7));
            }
            *(half4*)&Xt[((size_t)b * DD + d0 + tdr) * NN + n0 + tn4] = xo;
        }
        // compute chunk it from buffer cur
        half8 af[4], bf[4];
        #pragma unroll
        for (int mi = 0; mi < 4; mi++)
            af[mi] = *(half8*)((_Float16*)Xs[cur] + (mi * 16 + l15) * 32 + qs);
        #pragma unroll
        for (int ki = 0; ki < 4; ki++)
            bf[ki] = *(half8*)((_Float16*)Cs[cur] + (wk + ki * 16 + l15) * 32 + qs);
        #pragma unroll
        for (int mi = 0; mi < 4; mi++)
            #pragma unroll
            for (int ki = 0; ki < 4; ki++)
                acc[mi][ki] = __builtin_amdgcn_mfma_f32_16x16x32_f16(af[mi], bf[ki], acc[mi][ki], 0, 0, 0);
        if (it + 1 < 24) { __syncthreads(); cur ^= 1; }
    }

    // ---- softmax over k=512 ----
    // logit = 2*acc - cs;  k = wk + ki*16 + l15, token = mi*16 + quad*4 + r
    float pmax[4][4];
    #pragma unroll
    for (int mi = 0; mi < 4; mi++)
        #pragma unroll
        for (int r = 0; r < 4; r++) {
            float m = -1e30f;
            #pragma unroll
            for (int ki = 0; ki < 4; ki++)
                m = fmaxf(m, 2.f * acc[mi][ki][r] - cs[ki]);
            pmax[mi][r] = m;
        }
    #pragma unroll
    for (int off = 1; off < 16; off <<= 1)
        #pragma unroll
        for (int mi = 0; mi < 4; mi++)
            #pragma unroll
            for (int r = 0; r < 4; r++)
                pmax[mi][r] = fmaxf(pmax[mi][r], __shfl_xor(pmax[mi][r], off));
    if (l15 == 0) {
        #pragma unroll
        for (int mi = 0; mi < 4; mi++)
            #pragma unroll
            for (int r = 0; r < 4; r++)
                redbuf[w][mi * 16 + quad * 4 + r] = pmax[mi][r];
    }
    __syncthreads();
    if (t < 64) {
        float g = redbuf[0][t];
        #pragma unroll
        for (int wv = 1; wv < 8; wv++) g = fmaxf(g, redbuf[wv][t]);
        gred[t] = g;
    }
    __syncthreads();
    float gmax[4][4];
    #pragma unroll
    for (int mi = 0; mi < 4; mi++)
        #pragma unroll
        for (int r = 0; r < 4; r++)
            gmax[mi][r] = gred[mi * 16 + quad * 4 + r];   // broadcast read

    float psum[4][4] = {};
    #pragma unroll
    for (int mi = 0; mi < 4; mi++)
        #pragma unroll
        for (int ki = 0; ki < 4; ki++) {
            floatx4 e;
            #pragma unroll
            for (int r = 0; r < 4; r++) {
                e[r] = __expf(2.f * acc[mi][ki][r] - cs[ki] - gmax[mi][r]);
                psum[mi][r] += e[r];
            }
            acc[mi][ki] = e;
        }
    #pragma unroll
    for (int off = 1; off < 16; off <<= 1)
        #pragma unroll
        for (int mi = 0; mi < 4; mi++)
            #pragma unroll
            for (int r = 0; r < 4; r++)
                psum[mi][r] += __shfl_xor(psum[mi][r], off);
    if (l15 == 0) {
        #pragma unroll
        for (int mi = 0; mi < 4; mi++)
            #pragma unroll
            for (int r = 0; r < 4; r++)
                redbuf[w][mi * 16 + quad * 4 + r] = psum[mi][r];
    }
    __syncthreads();
    if (t < 64) {
        float s = redbuf[0][t];
        #pragma unroll
        for (int wv = 1; wv < 8; wv++) s += redbuf[wv][t];
        gred[t] = 1.f / s;
    }
    __syncthreads();
    float ginv[4][4];
    #pragma unroll
    for (int mi = 0; mi < 4; mi++)
        #pragma unroll
        for (int r = 0; r < 4; r++)
            ginv[mi][r] = gred[mi * 16 + quad * 4 + r];

    // scale + transposed store: St[b][k][n]
    #pragma unroll
    for (int mi = 0; mi < 4; mi++)
        #pragma unroll
        for (int ki = 0; ki < 4; ki++) {
            half4 s4;
            #pragma unroll
            for (int r = 0; r < 4; r++)
                s4[r] = (_Float16)(acc[mi][ki][r] * ginv[mi][r]);
            int k = wk + ki * 16 + l15;
            *(half4*)&St[((size_t)b * KK + k) * NN + n0 + mi * 16 + quad * 4] = s4;
        }
}

// ---------------------------------------------------------------------------
// GEMM2 (proven v3): out[b][k][d] = sum_n St[b][k][n] * Xt[b][d][n]
// 128x128 tile, BK=32, double-buffered LDS + 2-phase pipeline + XOR swizzle
// (linear lds-dma dest, pre-swizzled source), one __syncthreads per K-step.
// ---------------------------------------------------------------------------
__global__ __launch_bounds__(256, 4) void gemm2_mfma(const _Float16* __restrict__ St,
                                                     const _Float16* __restrict__ Xt,
                                                     float* __restrict__ out) {
    __shared__ _Float16 As[2][128][32];  // 16 KB
    __shared__ _Float16 Bs[2][128][32];  // 16 KB

    const int d0 = blockIdx.x * 128;
    const int k0 = blockIdx.y * 128;
    const int b = blockIdx.z;
    const int t = threadIdx.x;
    const int wave = t >> 6;
    const int lane = t & 63;
    const int wm = (wave >> 1) * 64;
    const int wn = (wave & 1) * 64;
    const int l15 = lane & 15;
    const int quad = lane >> 4;
    const int qs = (quad ^ ((l15 >> 1) & 3)) * 8;

    const int cr = t >> 2;                       // row within 64-row group
    const int cq = (t & 3) ^ ((t >> 3) & 3);     // swizzled source col-chunk

    floatx4 acc[4][4] = {};

    const _Float16* Abase = St + ((size_t)b * KK + k0) * NN;
    const _Float16* Bbase = Xt + ((size_t)b * DD + d0) * NN;

    // prologue: stage chunk 0
    #pragma unroll
    for (int c = 0; c < 2; c++) {
        load_lds16(Abase + (size_t)(c * 64 + cr) * NN + cq * 8,
                   (_Float16*)As[0] + (c * 256 + t) * 8);
        load_lds16(Bbase + (size_t)(c * 64 + cr) * NN + cq * 8,
                   (_Float16*)Bs[0] + (c * 256 + t) * 8);
    }
    __syncthreads();

    int cur = 0;
    for (int it = 0; it < 32; ++it) {
        if (it + 1 < 32) {
            const int n0 = (it + 1) * 32;
            #pragma unroll
            for (int c = 0; c < 2; c++) {
                load_lds16(Abase + (size_t)(c * 64 + cr) * NN + n0 + cq * 8,
                           (_Float16*)As[cur ^ 1] + (c * 256 + t) * 8);
                load_lds16(Bbase + (size_t)(c * 64 + cr) * NN + n0 + cq * 8,
                           (_Float16*)Bs[cur ^ 1] + (c * 256 + t) * 8);
            }
        }
        half8 af[4], bf[4];
        #pragma unroll
        for (int i = 0; i < 4; i++) af[i] = *(half8*)&As[cur][wm + i * 16 + l15][qs];
        #pragma unroll
        for (int i = 0; i < 4; i++) bf[i] = *(half8*)&Bs[cur][wn + i * 16 + l15][qs];
        #pragma unroll
        for (int mi = 0; mi < 4; mi++)
            #pragma unroll
            for (int ni = 0; ni < 4; ni++)
                acc[mi][ni] = __builtin_amdgcn_mfma_f32_16x16x32_f16(af[mi], bf[ni], acc[mi][ni], 0, 0, 0);
        if (it + 1 < 32) { __syncthreads(); cur ^= 1; }
    }

    #pragma unroll
    for (int ni = 0; ni < 4; ni++) {
        #pragma unroll
        for (int mi = 0; mi < 4; mi++) {
            int k = k0 + wm + mi * 16 + quad * 4;
            int d = d0 + wn + ni * 16 + l15;
            float* op = out + ((size_t)b * KK + k) * DD + d;
            floatx4 a = acc[mi][ni];
            op[0 * DD] = a[0];
            op[1 * DD] = a[1];
            op[2 * DD] = a[2];
            op[3 * DD] = a[3];
        }
    }
}

// ---------------------------------------------------------------------------
extern "C" void kernel_launch(void* const* d_in, const int* in_sizes, int n_in,
                              void* d_out, int out_size, void* d_ws, size_t ws_size,
                              hipStream_t stream) {
    const float* x  = (const float*)d_in[0];   // [B,N,D] fp32
    const float* cb = (const float*)d_in[1];   // [K,D] fp32
    float* out = (float*)d_out;                // [B,K,D] fp32

    char* ws = (char*)d_ws;
    float*    csq = (float*)ws;                                   // 4 KB
    _Float16* Cbh = (_Float16*)(ws + 4096);                       // 768 KB
    _Float16* Xt  = (_Float16*)(ws + 4096 + 786432);              // 48 MB [b][d][n]
    _Float16* St  = (_Float16*)(ws + 4096 + 786432 + 50331648);   // 32 MB [b][k][n]

    // codebook prep (merged cast + csq)
    prep_codebook<<<KK, 256, 0, stream>>>(cb, Cbh, csq);

    // fused logits + softmax -> St (fp16 [b][k][n]) AND X transpose -> Xt
    fused_logits_softmax<<<MM / 64, 512, 0, stream>>>(x, Cbh, csq, St, Xt);

    // aggregate
    gemm2_mfma<<<dim3(DD / 128, KK / 128, BB), 256, 0, stream>>>(St, Xt, out);
}